// Round 1
// baseline (755.727 us; speedup 1.0000x reference)
//
#include <hip/hip_runtime.h>
#include <hip/hip_bf16.h>

#define NTOK 16384
#define DM 1024
#define BM 128
#define BN 128
#define BK 64

typedef __attribute__((ext_vector_type(8))) short short8;
typedef __attribute__((ext_vector_type(4))) float floatx4;

// ---------- helpers ----------

// round-to-nearest-even fp32 -> bf16 bits (inputs are finite; no NaN handling needed)
__device__ __forceinline__ unsigned short f2bf(float x) {
  unsigned u = __float_as_uint(x);
  unsigned r = (u + 0x7fffu + ((u >> 16) & 1u)) >> 16;
  return (unsigned short)r;
}
__device__ __forceinline__ float bf2f(unsigned short b) {
  return __uint_as_float(((unsigned)b) << 16);
}

// Swizzled LDS byte offset for a [128 rows][64 bf16 cols] plane (row stride 128B).
// XOR the 16B-chunk index with (row&7) to break the stride-128B bank conflict
// (guide §6 G4: row-major D=128B tiles are a 16-way conflict on ds_read_b128).
__device__ __forceinline__ unsigned lds_off(unsigned r, unsigned c) {
  return r * 128u + ((((c >> 3) ^ r) & 7u) << 4) + (c & 7u) * 2u;
}

// split one float4 into bf16-hi and bf16-lo quads, write 8B each to swizzled LDS
__device__ __forceinline__ void split_write(char* ph, char* pl, float4 f) {
  unsigned short h0 = f2bf(f.x), h1 = f2bf(f.y), h2 = f2bf(f.z), h3 = f2bf(f.w);
  unsigned short l0 = f2bf(f.x - bf2f(h0));
  unsigned short l1 = f2bf(f.y - bf2f(h1));
  unsigned short l2 = f2bf(f.z - bf2f(h2));
  unsigned short l3 = f2bf(f.w - bf2f(h3));
  uint2 hv, lv;
  hv.x = (unsigned)h0 | ((unsigned)h1 << 16);
  hv.y = (unsigned)h2 | ((unsigned)h3 << 16);
  lv.x = (unsigned)l0 | ((unsigned)l1 << 16);
  lv.y = (unsigned)l2 | ((unsigned)l3 << 16);
  *(uint2*)ph = hv;
  *(uint2*)pl = lv;
}

// ---------- GEMM: C[M=16384, N=1024] = A[M,1024] @ W[N=1024,1024]^T + bias ----------
// Split-bf16 3-pass: C ~= Ah*Bh + Ah*Bl + Al*Bh  (drops Al*Bl, ~2^-18 rel err)
// 128x128 tile, BK=64, 4 waves of 64 (2x2), each wave 64x64 = 4x4 frags of 16x16.
__global__ __launch_bounds__(256, 2) void gemm_nt_split(
    const float* __restrict__ A, const float* __restrict__ W,
    const float* __restrict__ bias, float* __restrict__ C) {
  __shared__ __align__(16) char smem[4 * 16384];  // Ah, Al, Bh, Bl planes (64 KiB)
  char* Ah = smem;
  char* Al = smem + 16384;
  char* Bh = smem + 32768;
  char* Bl = smem + 49152;

  const int tid = threadIdx.x;
  const int m0 = blockIdx.y * BM;
  const int n0 = blockIdx.x * BN;
  const int lane = tid & 63;
  const int wave = tid >> 6;
  const int wm = (wave >> 1) * 64;  // wave's row offset in tile
  const int wn = (wave & 1) * 64;   // wave's col offset in tile
  const int fr = lane & 15;         // fragment row/col within 16
  const int fq = lane >> 4;         // k-chunk selector (0..3)

  floatx4 acc[4][4];
  floatx4 zero = {0.f, 0.f, 0.f, 0.f};
#pragma unroll
  for (int i = 0; i < 4; ++i)
#pragma unroll
    for (int j = 0; j < 4; ++j) acc[i][j] = zero;

  const int rb = tid >> 4;  // staging base row (0..15, step 16 below)
  const int c4 = tid & 15;  // staging float4 column index
  const float* ag = A + (long)(m0 + rb) * DM + c4 * 4;
  const float* wg = W + (long)(n0 + rb) * DM + c4 * 4;

  for (int kt = 0; kt < DM; kt += BK) {
    // stage: global fp32 -> (bf16 hi, bf16 lo) planes in swizzled LDS
#pragma unroll
    for (int i = 0; i < 8; ++i) {
      float4 fa = *(const float4*)(ag + (long)i * 16 * DM + kt);
      float4 fb = *(const float4*)(wg + (long)i * 16 * DM + kt);
      unsigned off = lds_off(rb + i * 16, c4 * 4);
      split_write(Ah + off, Al + off, fa);
      split_write(Bh + off, Bl + off, fb);
    }
    __syncthreads();

    // compute: 2 k-substeps of 32, 16 frag-pairs, 3 MFMA passes each
#pragma unroll
    for (int ks = 0; ks < 2; ++ks) {
      short8 ah[4], al[4], bh[4], bl[4];
#pragma unroll
      for (int i = 0; i < 4; ++i) {
        unsigned oa = lds_off(wm + i * 16 + fr, ks * 32 + fq * 8);
        ah[i] = *(short8*)(Ah + oa);
        al[i] = *(short8*)(Al + oa);
        unsigned ob = lds_off(wn + i * 16 + fr, ks * 32 + fq * 8);
        bh[i] = *(short8*)(Bh + ob);
        bl[i] = *(short8*)(Bl + ob);
      }
#pragma unroll
      for (int mi = 0; mi < 4; ++mi)
#pragma unroll
        for (int ni = 0; ni < 4; ++ni) {
          acc[mi][ni] = __builtin_amdgcn_mfma_f32_16x16x32_bf16(ah[mi], bh[ni], acc[mi][ni], 0, 0, 0);
          acc[mi][ni] = __builtin_amdgcn_mfma_f32_16x16x32_bf16(ah[mi], bl[ni], acc[mi][ni], 0, 0, 0);
          acc[mi][ni] = __builtin_amdgcn_mfma_f32_16x16x32_bf16(al[mi], bh[ni], acc[mi][ni], 0, 0, 0);
        }
    }
    __syncthreads();
  }

  // epilogue: C/D layout col=lane&15, row=(lane>>4)*4+reg (guide §3, m89-verified)
#pragma unroll
  for (int ni = 0; ni < 4; ++ni) {
    const int col = n0 + wn + ni * 16 + fr;
    const float bv = bias[col];
#pragma unroll
    for (int mi = 0; mi < 4; ++mi) {
      const int row0 = m0 + wm + mi * 16 + fq * 4;
#pragma unroll
      for (int j = 0; j < 4; ++j)
        C[(long)(row0 + j) * DM + col] = acc[mi][ni][j] + bv;
    }
  }
}

// ---------- per-token attention over the HEADS axis (16x16 per token) ----------
// One block (256 thr) per token. Reads Qp/Kp/Vp rows, writes result in-place over Qp.
__global__ __launch_bounds__(256) void attn_heads(float* __restrict__ Q,
                                                  const float* __restrict__ K,
                                                  const float* __restrict__ V) {
  __shared__ float qs[16][68];  // stride 68: 2-way-max bank aliasing (free, m136)
  __shared__ float ks[16][68];
  __shared__ float vs[16][68];
  __shared__ float pw[16][17];
  const int t = blockIdx.x;
  const int tid = threadIdx.x;
  const long base = (long)t * DM;
  const int h = tid >> 4;          // head 0..15
  const int d0 = (tid & 15) * 4;   // dim quad

  {
    float4 fq = *(const float4*)(Q + base + tid * 4);
    float4 fk = *(const float4*)(K + base + tid * 4);
    float4 fv = *(const float4*)(V + base + tid * 4);
    *(float4*)&qs[h][d0] = fq;
    *(float4*)&ks[h][d0] = fk;
    *(float4*)&vs[h][d0] = fv;
  }
  __syncthreads();

  // scores[h][g] = dot64(qh[h], kh[g]) / sqrt(64)
  const int g = tid & 15;
  float s = 0.f;
#pragma unroll
  for (int d = 0; d < 64; ++d) s += qs[h][d] * ks[g][d];
  s *= 0.125f;

  // softmax over g (groups of 16 lanes)
  float mx = s;
#pragma unroll
  for (int off = 8; off > 0; off >>= 1) mx = fmaxf(mx, __shfl_xor(mx, off, 16));
  float e = __expf(s - mx);
  float den = e;
#pragma unroll
  for (int off = 8; off > 0; off >>= 1) den += __shfl_xor(den, off, 16);
  pw[h][g] = e / den;
  __syncthreads();

  // out[h][d] = sum_g pw[h][g] * vh[g][d]; write back over Q (safe: qs already staged)
  float4 o = make_float4(0.f, 0.f, 0.f, 0.f);
#pragma unroll
  for (int g2 = 0; g2 < 16; ++g2) {
    float p = pw[h][g2];
    float4 vv = *(const float4*)&vs[g2][d0];
    o.x += p * vv.x;
    o.y += p * vv.y;
    o.z += p * vv.z;
    o.w += p * vv.w;
  }
  *(float4*)(Q + base + tid * 4) = o;
}

// ---------- launch ----------
extern "C" void kernel_launch(void* const* d_in, const int* in_sizes, int n_in,
                              void* d_out, int out_size, void* d_ws, size_t ws_size,
                              hipStream_t stream) {
  const float* q  = (const float*)d_in[0];
  const float* k  = (const float*)d_in[1];
  const float* v  = (const float*)d_in[2];
  const float* Wq = (const float*)d_in[3];
  const float* bq = (const float*)d_in[4];
  const float* Wk = (const float*)d_in[5];
  const float* bk = (const float*)d_in[6];
  const float* Wv = (const float*)d_in[7];
  const float* bv = (const float*)d_in[8];
  const float* Wo = (const float*)d_in[9];
  const float* bo = (const float*)d_in[10];

  float* Qp = (float*)d_ws;                       // 64 MB
  float* Kp = Qp + (size_t)NTOK * DM;             // 64 MB
  float* Vp = Kp + (size_t)NTOK * DM;             // 64 MB  (192 MB total)

  dim3 ggrid(DM / BN, NTOK / BM);  // (8, 128)
  dim3 gblk(256);

  gemm_nt_split<<<ggrid, gblk, 0, stream>>>(q, Wq, bq, Qp);
  gemm_nt_split<<<ggrid, gblk, 0, stream>>>(k, Wk, bk, Kp);
  gemm_nt_split<<<ggrid, gblk, 0, stream>>>(v, Wv, bv, Vp);
  attn_heads<<<dim3(NTOK), dim3(256), 0, stream>>>(Qp, Kp, Vp);
  gemm_nt_split<<<ggrid, gblk, 0, stream>>>(Qp, Wo, bo, (float*)d_out);
}

// Round 2
// 526.428 us; speedup vs baseline: 1.4356x; 1.4356x over previous
//
#include <hip/hip_runtime.h>

#define NTOK 16384
#define DM 1024
#define BM 128
#define BN 128
#define BK 64

typedef _Float16 h16;
typedef __attribute__((ext_vector_type(8))) _Float16 half8;
typedef __attribute__((ext_vector_type(4))) _Float16 half4;
typedef __attribute__((ext_vector_type(4))) float floatx4;

// Swizzled LDS byte offset for a [128 rows][64 fp16 cols] plane (row stride 128B).
// XOR the 16B-chunk index with (row&7) — verified conflict-free (R0: SQ_LDS_BANK_CONFLICT=0).
__device__ __forceinline__ unsigned lds_off(unsigned r, unsigned c) {
  return r * 128u + ((((c >> 3) ^ r) & 7u) << 4) + (c & 7u) * 2u;
}

// fp32x4 -> fp16x4 (RNE via _Float16 cast), packed as uint2 for an 8B LDS write
__device__ __forceinline__ uint2 f4h4(float4 f) {
  unsigned short a = __builtin_bit_cast(unsigned short, (h16)f.x);
  unsigned short b = __builtin_bit_cast(unsigned short, (h16)f.y);
  unsigned short c = __builtin_bit_cast(unsigned short, (h16)f.z);
  unsigned short d = __builtin_bit_cast(unsigned short, (h16)f.w);
  uint2 r;
  r.x = (unsigned)a | ((unsigned)b << 16);
  r.y = (unsigned)c | ((unsigned)d << 16);
  return r;
}

// ---------- GEMM: C[16384,1024] = A @ W^T + bias, single-pass fp16 MFMA ----------
// 128x128 tile, BK=64, 4 waves (2x2), each wave 64x64 = 4x4 frags of 16x16x32_f16.
// AHALF: A is fp16 (GEMM4, attn output). OHALF: C written as fp16 (GEMM1-3).
template <bool AHALF, bool OHALF>
__global__ __launch_bounds__(256, 4) void gemm_h(const void* __restrict__ Aptr,
                                                 const float* __restrict__ W,
                                                 const float* __restrict__ bias,
                                                 void* __restrict__ Cptr) {
  __shared__ __align__(16) char smem[32768];  // A plane 16K, B plane 16K
  char* Ap = smem;
  char* Bp = smem + 16384;

  const int tid = threadIdx.x;

  // XCD-aware bijective swizzle: grid is (8,128)=1024 blocks; XCD ~ bid%8.
  // Give each XCD 16 consecutive row-panels; walk the 8 column-blocks of a
  // panel consecutively on ONE XCD so the 512KB A-panel stays L2-resident.
  const int bid = (int)(blockIdx.x + gridDim.x * blockIdx.y);
  const int xcd = bid & 7, ch = bid >> 3;
  const int m0 = (xcd * 16 + (ch >> 3)) * BM;
  const int n0 = (ch & 7) * BN;

  const int lane = tid & 63;
  const int wave = tid >> 6;
  const int wm = (wave >> 1) * 64;
  const int wn = (wave & 1) * 64;
  const int fr = lane & 15;
  const int fq = lane >> 4;

  floatx4 acc[4][4] = {};

  // staging maps
  const int rb = tid >> 4, c4 = tid & 15;  // fp32 source: 16 rows x 16 float4
  const int rA = tid >> 3, c8 = tid & 7;   // fp16 source: 32 rows x 8 half8

  const float* wg = W + (long)(n0 + rb) * DM + c4 * 4;
  const float* agf = AHALF ? nullptr : (const float*)Aptr + (long)(m0 + rb) * DM + c4 * 4;
  const h16* agh = AHALF ? (const h16*)Aptr + (long)(m0 + rA) * DM + c8 * 8 : nullptr;

  for (int kt = 0; kt < DM; kt += BK) {
    // stage A
    if constexpr (AHALF) {
#pragma unroll
      for (int i = 0; i < 4; ++i) {
        uint4 u = *(const uint4*)(agh + (long)i * 32 * DM + kt);
        *(uint4*)(Ap + lds_off(rA + i * 32, c8 * 8)) = u;
      }
    } else {
#pragma unroll
      for (int i = 0; i < 8; ++i) {
        float4 fa = *(const float4*)(agf + (long)i * 16 * DM + kt);
        *(uint2*)(Ap + lds_off(rb + i * 16, c4 * 4)) = f4h4(fa);
      }
    }
    // stage W (always fp32 -> fp16)
#pragma unroll
    for (int i = 0; i < 8; ++i) {
      float4 fb = *(const float4*)(wg + (long)i * 16 * DM + kt);
      *(uint2*)(Bp + lds_off(rb + i * 16, c4 * 4)) = f4h4(fb);
    }
    __syncthreads();

#pragma unroll
    for (int ks = 0; ks < 2; ++ks) {
      half8 af[4], bf[4];
#pragma unroll
      for (int i = 0; i < 4; ++i) {
        af[i] = *(half8*)(Ap + lds_off(wm + i * 16 + fr, ks * 32 + fq * 8));
        bf[i] = *(half8*)(Bp + lds_off(wn + i * 16 + fr, ks * 32 + fq * 8));
      }
#pragma unroll
      for (int mi = 0; mi < 4; ++mi)
#pragma unroll
        for (int ni = 0; ni < 4; ++ni)
          acc[mi][ni] = __builtin_amdgcn_mfma_f32_16x16x32_f16(af[mi], bf[ni], acc[mi][ni], 0, 0, 0);
    }
    __syncthreads();
  }

  // epilogue: C/D layout col=lane&15, row=(lane>>4)*4+reg (m89-verified, R0-passed)
#pragma unroll
  for (int ni = 0; ni < 4; ++ni) {
    const int col = n0 + wn + ni * 16 + fr;
    const float bv = bias[col];
#pragma unroll
    for (int mi = 0; mi < 4; ++mi) {
      const int row0 = m0 + wm + mi * 16 + fq * 4;
#pragma unroll
      for (int j = 0; j < 4; ++j) {
        const float val = acc[mi][ni][j] + bv;
        if constexpr (OHALF)
          ((h16*)Cptr)[(long)(row0 + j) * DM + col] = (h16)val;
        else
          ((float*)Cptr)[(long)(row0 + j) * DM + col] = val;
      }
    }
  }
}

// ---------- per-token attention over the HEADS axis (16x16 per token), fp16 I/O ----------
__global__ __launch_bounds__(256) void attn_heads_h(h16* __restrict__ Q,
                                                    const h16* __restrict__ K,
                                                    const h16* __restrict__ V) {
  __shared__ float qs[16][68];
  __shared__ float ks[16][68];
  __shared__ float vs[16][68];
  __shared__ float pw[16][17];
  const int t = blockIdx.x;
  const int tid = threadIdx.x;
  const long base = (long)t * DM + tid * 4;
  const int h = tid >> 4;
  const int d0 = (tid & 15) * 4;

  {
    half4 fq = *(const half4*)(Q + base);
    half4 fk = *(const half4*)(K + base);
    half4 fv = *(const half4*)(V + base);
    *(float4*)&qs[h][d0] = make_float4((float)fq[0], (float)fq[1], (float)fq[2], (float)fq[3]);
    *(float4*)&ks[h][d0] = make_float4((float)fk[0], (float)fk[1], (float)fk[2], (float)fk[3]);
    *(float4*)&vs[h][d0] = make_float4((float)fv[0], (float)fv[1], (float)fv[2], (float)fv[3]);
  }
  __syncthreads();

  const int g = tid & 15;
  float s = 0.f;
#pragma unroll
  for (int d = 0; d < 64; ++d) s += qs[h][d] * ks[g][d];
  s *= 0.125f;

  float mx = s;
#pragma unroll
  for (int off = 8; off > 0; off >>= 1) mx = fmaxf(mx, __shfl_xor(mx, off, 16));
  float e = __expf(s - mx);
  float den = e;
#pragma unroll
  for (int off = 8; off > 0; off >>= 1) den += __shfl_xor(den, off, 16);
  pw[h][g] = e / den;
  __syncthreads();

  float4 o = make_float4(0.f, 0.f, 0.f, 0.f);
#pragma unroll
  for (int g2 = 0; g2 < 16; ++g2) {
    const float p = pw[h][g2];
    o.x += p * vs[g2][d0 + 0];
    o.y += p * vs[g2][d0 + 1];
    o.z += p * vs[g2][d0 + 2];
    o.w += p * vs[g2][d0 + 3];
  }
  half4 oh;
  oh[0] = (h16)o.x; oh[1] = (h16)o.y; oh[2] = (h16)o.z; oh[3] = (h16)o.w;
  *(half4*)(Q + base) = oh;  // in-place over Q (fully staged to LDS above)
}

// ---------- launch ----------
extern "C" void kernel_launch(void* const* d_in, const int* in_sizes, int n_in,
                              void* d_out, int out_size, void* d_ws, size_t ws_size,
                              hipStream_t stream) {
  const float* q  = (const float*)d_in[0];
  const float* k  = (const float*)d_in[1];
  const float* v  = (const float*)d_in[2];
  const float* Wq = (const float*)d_in[3];
  const float* bq = (const float*)d_in[4];
  const float* Wk = (const float*)d_in[5];
  const float* bk = (const float*)d_in[6];
  const float* Wv = (const float*)d_in[7];
  const float* bv = (const float*)d_in[8];
  const float* Wo = (const float*)d_in[9];
  const float* bo = (const float*)d_in[10];

  h16* Qp = (h16*)d_ws;                    // 32 MB
  h16* Kp = Qp + (size_t)NTOK * DM;        // 32 MB
  h16* Vp = Kp + (size_t)NTOK * DM;        // 32 MB (96 MB total)

  dim3 ggrid(DM / BN, NTOK / BM);  // (8, 128)
  dim3 gblk(256);

  gemm_h<false, true><<<ggrid, gblk, 0, stream>>>(q, Wq, bq, Qp);
  gemm_h<false, true><<<ggrid, gblk, 0, stream>>>(k, Wk, bk, Kp);
  gemm_h<false, true><<<ggrid, gblk, 0, stream>>>(v, Wv, bv, Vp);
  attn_heads_h<<<dim3(NTOK), gblk, 0, stream>>>(Qp, Kp, Vp);
  gemm_h<true, false><<<ggrid, gblk, 0, stream>>>(Qp, Wo, bo, (float*)d_out);
}

// Round 3
// 448.663 us; speedup vs baseline: 1.6844x; 1.1733x over previous
//
#include <hip/hip_runtime.h>

#define NTOK 16384
#define DM 1024
#define BM 128
#define BN 128
#define BK 64

typedef _Float16 h16;
typedef __attribute__((ext_vector_type(8))) _Float16 half8;
typedef __attribute__((ext_vector_type(4))) _Float16 half4;
typedef __attribute__((ext_vector_type(4))) float floatx4;

// Swizzled LDS byte offset for a [128 rows][64 fp16 cols] plane (row stride 128B).
// XOR 16B-chunk index with (row&7) — verified conflict-free (R1/R2: SQ_LDS_BANK_CONFLICT=0).
__device__ __forceinline__ unsigned lds_off(unsigned r, unsigned c) {
  return r * 128u + ((((c >> 3) ^ r) & 7u) << 4) + (c & 7u) * 2u;
}

// async global->LDS, 16B per lane; LDS dest is wave-uniform base + lane*16 (HW rule)
__device__ __forceinline__ void gload16(const h16* g, char* l) {
  __builtin_amdgcn_global_load_lds((const __attribute__((address_space(1))) unsigned*)g,
                                   (__attribute__((address_space(3))) unsigned*)l, 16, 0, 0);
}

// ---------- GEMM: C[16384,1024] = A @ W^T + bias, fp16 in, m97 structure ----------
// 128x128 tile, BK=64, 4 waves (2x2), 16x16x32_f16 MFMA, global_load_lds staging
// with pre-swizzled GLOBAL source addresses + linear LDS dest (m173 pattern).
template <bool OHALF>
__global__ __launch_bounds__(256, 4) void gemm_hh(const h16* __restrict__ A,
                                                  const h16* __restrict__ W,
                                                  const float* __restrict__ bias,
                                                  void* __restrict__ Cptr) {
  __shared__ __align__(16) char smem[32768];  // A plane 16K, B plane 16K
  char* Ap = smem;
  char* Bp = smem + 16384;

  const int tid = threadIdx.x;

  // XCD-aware bijective swizzle (R2-verified: FETCH 49MB): each XCD owns 16
  // consecutive row-panels; the 8 column-blocks of a panel stay on one XCD.
  const int bid = (int)(blockIdx.x + gridDim.x * blockIdx.y);
  const int xcd = bid & 7, ch = bid >> 3;
  const int m0 = (xcd * 16 + (ch >> 3)) * BM;
  const int n0 = (ch & 7) * BN;

  const int lane = tid & 63;
  const int wave = tid >> 6;
  const int wm = (wave >> 1) * 64;
  const int wn = (wave & 1) * 64;
  const int fr = lane & 15;
  const int fq = lane >> 4;

  floatx4 acc[4][4] = {};

  // staging addresses: wave w, issue i covers tile rows w*32+i*8 .. +8.
  // lane's row-in-8 lr = lane>>3; LDS chunk cc = lane&7 holds global column
  // chunk cc ^ (row&7); row&7 == lr, so swizzled chunk lc = (lane&7)^lr is
  // lane-constant. Linear LDS dest = plane + (w*4+i)*1024 + lane*16 (HW).
  const int lr = lane >> 3;
  const int lc = (lane & 7) ^ lr;
  const h16* ag = A + (long)(m0 + wave * 32 + lr) * DM + lc * 8;
  const h16* wg = W + (long)(n0 + wave * 32 + lr) * DM + lc * 8;
  char* const alds = Ap + wave * 4096;
  char* const blds = Bp + wave * 4096;

  for (int kt = 0; kt < DM; kt += BK) {
#pragma unroll
    for (int i = 0; i < 4; ++i) {
      gload16(ag + (long)(i * 8) * DM + kt, alds + i * 1024);
      gload16(wg + (long)(i * 8) * DM + kt, blds + i * 1024);
    }
    __syncthreads();  // drains vmcnt (gload_lds counted) + barrier

#pragma unroll
    for (int ks = 0; ks < 2; ++ks) {
      half8 af[4], bf[4];
#pragma unroll
      for (int i = 0; i < 4; ++i) {
        af[i] = *(half8*)(Ap + lds_off(wm + i * 16 + fr, ks * 32 + fq * 8));
        bf[i] = *(half8*)(Bp + lds_off(wn + i * 16 + fr, ks * 32 + fq * 8));
      }
#pragma unroll
      for (int mi = 0; mi < 4; ++mi)
#pragma unroll
        for (int ni = 0; ni < 4; ++ni)
          acc[mi][ni] = __builtin_amdgcn_mfma_f32_16x16x32_f16(af[mi], bf[ni], acc[mi][ni], 0, 0, 0);
    }
    __syncthreads();
  }

  // epilogue: C/D layout col=lane&15, row=(lane>>4)*4+reg (m89-verified, R1/R2-passed)
#pragma unroll
  for (int ni = 0; ni < 4; ++ni) {
    const int col = n0 + wn + ni * 16 + fr;
    const float bv = bias[col];
#pragma unroll
    for (int mi = 0; mi < 4; ++mi) {
      const int row0 = m0 + wm + mi * 16 + fq * 4;
#pragma unroll
      for (int j = 0; j < 4; ++j) {
        const float val = acc[mi][ni][j] + bv;
        if constexpr (OHALF)
          ((h16*)Cptr)[(long)(row0 + j) * DM + col] = (h16)val;
        else
          ((float*)Cptr)[(long)(row0 + j) * DM + col] = val;
      }
    }
  }
}

// ---------- fp32 -> fp16 converters (memory-bound, 8 elem/thread) ----------
__global__ __launch_bounds__(256) void cvt3(const float* __restrict__ a, const float* __restrict__ b,
                                            const float* __restrict__ c, h16* __restrict__ oa,
                                            h16* __restrict__ ob, h16* __restrict__ oc) {
  const long i = ((long)blockIdx.x * 256 + threadIdx.x) * 8;
  const float* s = blockIdx.y == 0 ? a : blockIdx.y == 1 ? b : c;
  h16* d = blockIdx.y == 0 ? oa : blockIdx.y == 1 ? ob : oc;
  float4 f0 = *(const float4*)(s + i);
  float4 f1 = *(const float4*)(s + i + 4);
  half8 h;
  h[0] = (h16)f0.x; h[1] = (h16)f0.y; h[2] = (h16)f0.z; h[3] = (h16)f0.w;
  h[4] = (h16)f1.x; h[5] = (h16)f1.y; h[6] = (h16)f1.z; h[7] = (h16)f1.w;
  *(half8*)(d + i) = h;
}

__global__ __launch_bounds__(256) void cvtW(const float* __restrict__ a, const float* __restrict__ b,
                                            const float* __restrict__ c, const float* __restrict__ e,
                                            h16* __restrict__ oa, h16* __restrict__ ob,
                                            h16* __restrict__ oc, h16* __restrict__ oe) {
  const long i = ((long)blockIdx.x * 256 + threadIdx.x) * 8;
  const float* s = blockIdx.y == 0 ? a : blockIdx.y == 1 ? b : blockIdx.y == 2 ? c : e;
  h16* d = blockIdx.y == 0 ? oa : blockIdx.y == 1 ? ob : blockIdx.y == 2 ? oc : oe;
  float4 f0 = *(const float4*)(s + i);
  float4 f1 = *(const float4*)(s + i + 4);
  half8 h;
  h[0] = (h16)f0.x; h[1] = (h16)f0.y; h[2] = (h16)f0.z; h[3] = (h16)f0.w;
  h[4] = (h16)f1.x; h[5] = (h16)f1.y; h[6] = (h16)f1.z; h[7] = (h16)f1.w;
  *(half8*)(d + i) = h;
}

// ---------- per-token attention over the HEADS axis (16x16 per token), fp16 I/O ----------
__global__ __launch_bounds__(256) void attn_heads_h(h16* __restrict__ Q,
                                                    const h16* __restrict__ K,
                                                    const h16* __restrict__ V) {
  __shared__ float qs[16][68];
  __shared__ float ks[16][68];
  __shared__ float vs[16][68];
  __shared__ float pw[16][17];
  const int t = blockIdx.x;
  const int tid = threadIdx.x;
  const long base = (long)t * DM + tid * 4;
  const int h = tid >> 4;
  const int d0 = (tid & 15) * 4;

  {
    half4 fq = *(const half4*)(Q + base);
    half4 fk = *(const half4*)(K + base);
    half4 fv = *(const half4*)(V + base);
    *(float4*)&qs[h][d0] = make_float4((float)fq[0], (float)fq[1], (float)fq[2], (float)fq[3]);
    *(float4*)&ks[h][d0] = make_float4((float)fk[0], (float)fk[1], (float)fk[2], (float)fk[3]);
    *(float4*)&vs[h][d0] = make_float4((float)fv[0], (float)fv[1], (float)fv[2], (float)fv[3]);
  }
  __syncthreads();

  const int g = tid & 15;
  float s = 0.f;
#pragma unroll
  for (int d = 0; d < 64; ++d) s += qs[h][d] * ks[g][d];
  s *= 0.125f;

  float mx = s;
#pragma unroll
  for (int off = 8; off > 0; off >>= 1) mx = fmaxf(mx, __shfl_xor(mx, off, 16));
  float e = __expf(s - mx);
  float den = e;
#pragma unroll
  for (int off = 8; off > 0; off >>= 1) den += __shfl_xor(den, off, 16);
  pw[h][g] = e / den;
  __syncthreads();

  float4 o = make_float4(0.f, 0.f, 0.f, 0.f);
#pragma unroll
  for (int g2 = 0; g2 < 16; ++g2) {
    const float p = pw[h][g2];
    o.x += p * vs[g2][d0 + 0];
    o.y += p * vs[g2][d0 + 1];
    o.z += p * vs[g2][d0 + 2];
    o.w += p * vs[g2][d0 + 3];
  }
  half4 oh;
  oh[0] = (h16)o.x; oh[1] = (h16)o.y; oh[2] = (h16)o.z; oh[3] = (h16)o.w;
  *(half4*)(Q + base) = oh;  // in-place over Q (fully staged to LDS above)
}

// ---------- launch ----------
extern "C" void kernel_launch(void* const* d_in, const int* in_sizes, int n_in,
                              void* d_out, int out_size, void* d_ws, size_t ws_size,
                              hipStream_t stream) {
  const float* q  = (const float*)d_in[0];
  const float* k  = (const float*)d_in[1];
  const float* v  = (const float*)d_in[2];
  const float* Wq = (const float*)d_in[3];
  const float* bq = (const float*)d_in[4];
  const float* Wk = (const float*)d_in[5];
  const float* bk = (const float*)d_in[6];
  const float* Wv = (const float*)d_in[7];
  const float* bv = (const float*)d_in[8];
  const float* Wo = (const float*)d_in[9];
  const float* bo = (const float*)d_in[10];

  const size_t NE = (size_t)NTOK * DM;   // 16.78M elems
  const size_t WE = (size_t)DM * DM;     // 1.05M elems
  h16* qh  = (h16*)d_ws;         // 32 MB
  h16* kh  = qh + NE;            // 32 MB
  h16* vh  = kh + NE;            // 32 MB
  h16* Wqh = vh + NE;            // 2 MB
  h16* Wkh = Wqh + WE;
  h16* Wvh = Wkh + WE;
  h16* Woh = Wvh + WE;
  h16* Qp  = Woh + WE;           // 32 MB   (total 136 MB)
  h16* Kp  = qh;                 // reuse: qh dead after GEMM1
  h16* Vp  = kh;                 // reuse: kh dead after GEMM2

  dim3 ggrid(DM / BN, NTOK / BM);  // (8, 128)
  dim3 gblk(256);

  cvt3<<<dim3(NE / (256 * 8), 3), gblk, 0, stream>>>(q, k, v, qh, kh, vh);
  cvtW<<<dim3(WE / (256 * 8), 4), gblk, 0, stream>>>(Wq, Wk, Wv, Wo, Wqh, Wkh, Wvh, Woh);

  gemm_hh<true><<<ggrid, gblk, 0, stream>>>(qh, Wqh, bq, Qp);
  gemm_hh<true><<<ggrid, gblk, 0, stream>>>(kh, Wkh, bk, Kp);
  gemm_hh<true><<<ggrid, gblk, 0, stream>>>(vh, Wvh, bv, Vp);
  attn_heads_h<<<dim3(NTOK), gblk, 0, stream>>>(Qp, Kp, Vp);
  gemm_hh<false><<<ggrid, gblk, 0, stream>>>(Qp, Woh, bo, (float*)d_out);
}